// Round 9
// baseline (147.951 us; speedup 1.0000x reference)
//
#include <hip/hip_runtime.h>
#include <math.h>

#define NB   32
#define CC   512
#define DD   2048
#define HWP  196
#define NHW  6272
#define HID  256

typedef _Float16 h8 __attribute__((ext_vector_type(8)));
typedef _Float16 h4 __attribute__((ext_vector_type(4)));
typedef float    f4 __attribute__((ext_vector_type(4)));
typedef float    f16v __attribute__((ext_vector_type(16)));
union F4H8 { f4 f; h8 h; };

// ================= prep: 864 blocks x 256 =================
// 0..511: hglb partials; 512..607: W2G(32x32 frags)/W1F(16x16 frags) pack; 608..863: lf transpose
__global__ __launch_bounds__(256) void prep_kernel(const float* __restrict__ lf,
                                                   const float* __restrict__ gf,
                                                   const float* __restrict__ W1,
                                                   const float* __restrict__ W2,
                                                   float* __restrict__ hpart,
                                                   _Float16* __restrict__ W2G,
                                                   _Float16* __restrict__ W1F,
                                                   _Float16* __restrict__ lf16T) {
    int bid = blockIdx.x, tid = threadIdx.x;
    if (bid < 512) {
        int i = bid >> 4, ky = bid & 15, k = tid;
        const float* g = gf + (size_t)i * DD + ky * 128;
        const float* w = W1 + (size_t)(ky * 128) * HID + k;
        float a0 = 0.f, a1 = 0.f, a2 = 0.f, a3 = 0.f;   // 4-way ILP
        #pragma unroll 8
        for (int r = 0; r < 128; r += 4) {
            a0 = fmaf(g[r + 0], w[(size_t)(r + 0) * HID], a0);
            a1 = fmaf(g[r + 1], w[(size_t)(r + 1) * HID], a1);
            a2 = fmaf(g[r + 2], w[(size_t)(r + 2) * HID], a2);
            a3 = fmaf(g[r + 3], w[(size_t)(r + 3) * HID], a3);
        }
        hpart[((size_t)i * 16 + ky) * HID + k] = (a0 + a1) + (a2 + a3);
    } else if (bid < 608) {
        int tg = (bid - 512) * 256 + tid;            // 0..24575
        if (tg < 8192) {
            // W2 pack for 32x32x16 A-frags: frag F = mt2*16 + ks (mt2 0..7, ks 0..15);
            // lane l elem r: A[m = mt2*32 + (l&31)][k = ks*16 + (l>>5)*8 + r] = W2[k][m]
            int t = tg, F = t >> 6, l = t & 63;
            int mt2 = F >> 4, ks = F & 15;
            int kb = ks * 16 + (l >> 5) * 8;
            int n  = mt2 * 32 + (l & 31);
            _Float16* o = W2G + (size_t)t * 8;
            #pragma unroll
            for (int j = 0; j < 8; j++) o[j] = (_Float16)W2[(size_t)(kb + j) * HID + n];
        } else {
            int t = tg - 8192, F = t >> 6, l = t & 63;
            int k2t = F >> 4, ks = F & 15;
            int kb = ks * 32 + (l >> 4) * 8;
            int n  = k2t * 16 + (l & 15);
            const float* W1c = W1 + (size_t)DD * HID;
            _Float16* o = W1F + (size_t)t * 8;
            #pragma unroll
            for (int j = 0; j < 8; j++) o[j] = (_Float16)W1c[(size_t)(kb + j) * HID + n];
        }
    } else {
        __shared__ _Float16 sT[64][HWP + 4];
        int b = bid - 608;                           // 0..255
        int n = b >> 3, c0 = (b & 7) * 64;
        for (int task = tid; task < 64 * 49; task += 256) {
            int c = task / 49, f = task - c * 49;
            f4 v = *(const f4*)&lf[((size_t)n * CC + c0 + c) * HWP + f * 4];
            h4 o = { (_Float16)v.x, (_Float16)v.y, (_Float16)v.z, (_Float16)v.w };
            *(h4*)&sT[c][f * 4] = o;
        }
        __syncthreads();
        for (int task = tid; task < 8 * HWP; task += 256) {
            int ch = task / HWP, p = task - ch * HWP;
            h8 o;
            #pragma unroll
            for (int cc = 0; cc < 8; cc++) o[cc] = sT[ch * 8 + cc][p];
            *(h8*)&lf16T[((size_t)(n * HWP + p)) * CC + c0 + ch * 8] = o;
        }
    }
}

// ================= hlocF: h_loc = lf16T @ W1[D:], MFMA, ROW-MAJOR [j][k2] output =================
__global__ __launch_bounds__(256, 2) void hlocF_kernel(const _Float16* __restrict__ lf16T,
                                                       const _Float16* __restrict__ W1F,
                                                       const float* __restrict__ hpart,
                                                       const float* __restrict__ b1,
                                                       _Float16* __restrict__ g16,
                                                       _Float16* __restrict__ hL) {
    if (blockIdx.x == 196) {
        int kh = blockIdx.y;
        for (int x = threadIdx.x; x < 16 * HID; x += 256) {
            int i = kh * 16 + (x >> 8), k = x & 255;
            float s = b1[k];
            #pragma unroll
            for (int ky = 0; ky < 16; ky++) s += hpart[((size_t)i * 16 + ky) * HID + k];
            g16[(size_t)i * HID + k] = (_Float16)s;
        }
        return;
    }
    __shared__ _Float16 sLf[32][CC + 16];
    int tid = threadIdx.x;
    int w = tid >> 6, l = tid & 63, quad = l >> 4, ln = l & 15;
    int j0 = blockIdx.x * 32;
    int khalf = blockIdx.y;

    #pragma unroll
    for (int s = 0; s < 8; s++) {
        int y = s * 256 + tid;
        int row = y >> 6, col = (y & 63) * 8;
        h8 v = *(const h8*)&lf16T[(size_t)(j0 + row) * CC + col];
        *(h8*)&sLf[row][col] = v;
    }

    F4H8 Af[32];
    {
        const f4* src = (const f4*)W1F + l;
        #pragma unroll
        for (int mt = 0; mt < 2; mt++)
            #pragma unroll
            for (int ks = 0; ks < 16; ks++)
                Af[mt * 16 + ks].f = src[(size_t)((khalf * 8 + w * 2 + mt) * 16 + ks) * 64];
    }
    __syncthreads();

    f4 acc[4] = {};
    #pragma unroll
    for (int ks = 0; ks < 16; ks++) {
        h8 bF[2];
        #pragma unroll
        for (int nt = 0; nt < 2; nt++)
            bF[nt] = *(const h8*)&sLf[nt * 16 + ln][ks * 32 + quad * 8];
        #pragma unroll
        for (int mt = 0; mt < 2; mt++)
            #pragma unroll
            for (int nt = 0; nt < 2; nt++)
                acc[mt * 2 + nt] = __builtin_amdgcn_mfma_f32_16x16x32_f16(Af[mt * 16 + ks].h, bF[nt], acc[mt * 2 + nt], 0, 0, 0);
    }

    // row-major packed h4 store: h_loc[j][k2], 4 consecutive k2 per reg group
    #pragma unroll
    for (int mt = 0; mt < 2; mt++)
        #pragma unroll
        for (int nt = 0; nt < 2; nt++) {
            int j  = j0 + nt * 16 + ln;
            int k2 = khalf * 128 + w * 32 + mt * 16 + quad * 4;
            h4 o = { (_Float16)acc[mt * 2 + nt][0], (_Float16)acc[mt * 2 + nt][1],
                     (_Float16)acc[mt * 2 + nt][2], (_Float16)acc[mt * 2 + nt][3] };
            *(h4*)&hL[(size_t)j * HID + k2] = o;
        }
}

// ================= score v8: 32x32x16 MFMA, 4 waves x 64 k2, 2 MFMAs per B-read =================
// R8 analysis: v7 (51us) was LDS-issue-bound at 1 read : 1 MFMA (1.605M reads ~ 31us pipe).
// 32x32x16 doubles FLOP per B-frag; 2 resident M-tiles double reuse again -> 401K reads
// (~8us) + 802K MFMA (~10.5us). Register budget honored by BLOCK SHAPE: 256 thr +
// launch_bounds(256,2) — the config under which hlocF already holds 128+ VGPRs spill-free.
// Af[2][16] = 128 VGPR, acc 32, ~190 total <= 256 cap (2 waves/SIMD, 2 blocks/CU).
// LDS sB is frag-ordered (v7's proven contiguous-read pattern, 0 conflicts); h1 =
// relu(hL+g) built during staging. IPB=2 amortizes Af. Grid (16, 98), 64-j tiles.
__global__ __launch_bounds__(256, 2)
void score_kernel(const _Float16* __restrict__ hL,
                  const _Float16* __restrict__ g16,
                  const _Float16* __restrict__ W2G,
                  const float* __restrict__ b2,
                  const float* __restrict__ W3,
                  const float* __restrict__ b3,
                  float* __restrict__ scores) {
    __shared__ _Float16 sB[64 * HID];     // 32 KB: h1 tile, frag-ordered for 32x32 B-reads
    __shared__ float sRed[4][68];         // [wave][j-local]
    int tid = threadIdx.x, w = tid >> 6, l = tid & 63;
    int hi = l >> 5, ln32 = l & 31;
    int i0 = blockIdx.x * 2, jt = blockIdx.y;   // jt 0..97
    int j0 = jt * 64;

    // A-frags: wave w owns k2-slice [w*64, w*64+64) = M-tiles 2w, 2w+1 (32 frags, 128 VGPR)
    F4H8 Af[2][16];
    {
        const f4* src = (const f4*)W2G + l;
        #pragma unroll
        for (int a = 0; a < 2; a++)
            #pragma unroll
            for (int ks = 0; ks < 16; ks++)
                Af[a][ks].f = src[(size_t)((w * 2 + a) * 16 + ks) * 64];
    }
    float bias3 = b3[0];

    // staging geometry: thread t -> row j = t>>2 (0..63), octets o = (t&3)*8 .. +7
    int sj = tid >> 2, so = (tid & 3) * 8;
    const _Float16* hrow = hL + ((size_t)(j0 + sj)) * HID + so * 8;

    #pragma unroll 1
    for (int ii = 0; ii < 2; ii++) {
        int i = i0 + ii;
        const _Float16* grow = g16 + (size_t)i * HID + so * 8;
        h8 z = {};
        // stage h1 = relu(hL + g) into frag-ordered LDS:
        // cell (j, o) -> frag(ntg=j>>5, ks=o>>1), lane (o&1)*32 + (j&31)
        #pragma unroll
        for (int oi = 0; oi < 8; oi++) {
            int o = so + oi;
            h8 hv = *(const h8*)&hrow[oi * 8];
            h8 gq = *(const h8*)&grow[oi * 8];
            h8 h1 = __builtin_elementwise_max(hv + gq, z);
            int cell = ((sj >> 5) * 16 + (o >> 1)) * 512 + ((o & 1) * 32 + (sj & 31)) * 8;
            *(h8*)&sB[cell] = h1;
        }
        __syncthreads();

        #pragma unroll 1
        for (int ntg = 0; ntg < 2; ntg++) {
            f16v acc[2] = {};
            #pragma unroll
            for (int ks = 0; ks < 16; ks++) {
                h8 bz = *(const h8*)&sB[((ntg * 16 + ks) * 64 + l) * 8];
                acc[0] = __builtin_amdgcn_mfma_f32_32x32x16_f16(Af[0][ks].h, bz, acc[0], 0, 0, 0);
                acc[1] = __builtin_amdgcn_mfma_f32_32x32x16_f16(Af[1][ks].h, bz, acc[1], 0, 0, 0);
            }
            // epilogue: C[m][n]: n=l&31 (j), m=(r&3)+8*(r>>2)+4*hi; s_j += relu(acc+b2)*W3
            float s = 0.f;
            #pragma unroll
            for (int a = 0; a < 2; a++) {
                int kb = w * 64 + a * 32 + 4 * hi;
                #pragma unroll
                for (int q = 0; q < 4; q++) {
                    f4 b2v = *(const f4*)&b2[kb + q * 8];
                    f4 w3v = *(const f4*)&W3[kb + q * 8];
                    s += fmaxf(acc[a][q * 4 + 0] + b2v.x, 0.f) * w3v.x
                       + fmaxf(acc[a][q * 4 + 1] + b2v.y, 0.f) * w3v.y
                       + fmaxf(acc[a][q * 4 + 2] + b2v.z, 0.f) * w3v.z
                       + fmaxf(acc[a][q * 4 + 3] + b2v.w, 0.f) * w3v.w;
                }
            }
            s += __shfl_xor(s, 32, 64);
            if (hi == 0) sRed[w][ntg * 32 + ln32] = s;
        }
        __syncthreads();
        if (tid < 64) {
            scores[(size_t)i * NHW + j0 + tid] =
                sRed[0][tid] + sRed[1][tid] + sRed[2][tid] + sRed[3][tid] + bias3;
        }
        // ii=0: next stage writes sB (readers done at barrier above); the post-stage
        // barrier orders this final read vs next epilogue's sRed writes.
    }
}

// ================= reduce: single-pass online masked log-mean-exp =================
__global__ __launch_bounds__(1024) void reduce_kernel(const float* __restrict__ scores,
                                                      float* __restrict__ out) {
    int i = blockIdx.x, tid = threadIdx.x;
    const float* row = scores + (size_t)i * NHW;
    const f4* row4 = (const f4*)row;                 // 1568 f4
    __shared__ float sM[16], sT[16], sO[16], sval[1];
    int q0 = i * 49, q1 = q0 + 49;
    float m = -1e30f, t = 0.f, o = 0.f;
    for (int q = tid; q < 1568; q += 1024) {
        f4 v = row4[q];
        float vm = fmaxf(fmaxf(v.x, v.y), fmaxf(v.z, v.w));
        float nm = fmaxf(m, vm);
        float sc = expf(m - nm);
        float e = expf(v.x - nm) + expf(v.y - nm) + expf(v.z - nm) + expf(v.w - nm);
        t = t * sc + e;
        o *= sc;
        if (q >= q0 && q < q1) o += e;
        m = nm;
    }
    #pragma unroll
    for (int off = 32; off > 0; off >>= 1) {
        float m2 = __shfl_xor(m, off, 64);
        float t2 = __shfl_xor(t, off, 64);
        float o2 = __shfl_xor(o, off, 64);
        float nm = fmaxf(m, m2);
        float sa = expf(m - nm), sb = expf(m2 - nm);
        t = t * sa + t2 * sb;
        o = o * sa + o2 * sb;
        m = nm;
    }
    if ((tid & 63) == 0) { sM[tid >> 6] = m; sT[tid >> 6] = t; sO[tid >> 6] = o; }
    __syncthreads();
    if (tid == 0) {
        float M = sM[0], T = sT[0], O = sO[0];
        for (int c = 1; c < 16; c++) {
            float nm = fmaxf(M, sM[c]);
            float sa = expf(M - nm), sb = expf(sM[c] - nm);
            T = T * sa + sT[c] * sb;
            O = O * sa + sO[c] * sb;
            M = nm;
        }
        float neg_mean = (T - O) / (float)(NHW - HWP) + 1e-10f;
        sval[0] = M + logf(neg_mean);
    }
    __syncthreads();
    float sub = sval[0];
    if (tid < HWP) out[(size_t)i * HWP + tid] = row[i * HWP + tid] - sub;
}

extern "C" void kernel_launch(void* const* d_in, const int* in_sizes, int n_in,
                              void* d_out, int out_size, void* d_ws, size_t ws_size,
                              hipStream_t stream) {
    const float* lf = (const float*)d_in[0];
    const float* gf = (const float*)d_in[1];
    const float* W1 = (const float*)d_in[2];
    const float* b1 = (const float*)d_in[3];
    const float* W2 = (const float*)d_in[4];
    const float* b2 = (const float*)d_in[5];
    const float* W3 = (const float*)d_in[6];
    const float* b3 = (const float*)d_in[7];
    float* out = (float*)d_out;

    char* ws = (char*)d_ws;
    _Float16* hL     = (_Float16*)ws;                      // 3,211,264 B  (row-major h_loc)
    _Float16* g16    = (_Float16*)(ws + 3211264);          // 16 KB
    _Float16* W2G    = (_Float16*)(ws + 3227648);          // 128 KB (32x32 frag pack)
    _Float16* W1F    = (_Float16*)(ws + 3358720);          // 256 KB
    _Float16* lf16T  = (_Float16*)(ws + 3620864);          // 6,422,528 B
    float*    scores = (float*)   (ws + 10043392);         // 802,816 B
    float*    hpart  = (float*)   (ws + 10846208);         // 524,288 B

    hipLaunchKernelGGL(prep_kernel, dim3(864), dim3(256), 0, stream,
                       lf, gf, W1, W2, hpart, W2G, W1F, lf16T);
    hipLaunchKernelGGL(hlocF_kernel, dim3(197, 2), dim3(256), 0, stream,
                       lf16T, W1F, hpart, b1, g16, hL);
    hipLaunchKernelGGL(score_kernel, dim3(16, 98), dim3(256), 0, stream,
                       hL, g16, W2G, b2, W3, b3, scores);
    hipLaunchKernelGGL(reduce_kernel, dim3(NB), dim3(1024), 0, stream, scores, out);
}

// Round 10
// 128.799 us; speedup vs baseline: 1.1487x; 1.1487x over previous
//
#include <hip/hip_runtime.h>
#include <math.h>

#define NB   32
#define CC   512
#define DD   2048
#define HWP  196
#define NHW  6272
#define HID  256

typedef _Float16 h8 __attribute__((ext_vector_type(8)));
typedef _Float16 h4 __attribute__((ext_vector_type(4)));
typedef float    f4 __attribute__((ext_vector_type(4)));
typedef float    f16v __attribute__((ext_vector_type(16)));
union F4H8 { f4 f; h8 h; };

// ================= prep: 864 blocks x 256 =================
// 0..511: hglb partials; 512..607: W2G(32x32 frags)/W1F(16x16 frags) pack; 608..863: lf transpose
__global__ __launch_bounds__(256) void prep_kernel(const float* __restrict__ lf,
                                                   const float* __restrict__ gf,
                                                   const float* __restrict__ W1,
                                                   const float* __restrict__ W2,
                                                   float* __restrict__ hpart,
                                                   _Float16* __restrict__ W2G,
                                                   _Float16* __restrict__ W1F,
                                                   _Float16* __restrict__ lf16T) {
    int bid = blockIdx.x, tid = threadIdx.x;
    if (bid < 512) {
        int i = bid >> 4, ky = bid & 15, k = tid;
        const float* g = gf + (size_t)i * DD + ky * 128;
        const float* w = W1 + (size_t)(ky * 128) * HID + k;
        float a0 = 0.f, a1 = 0.f, a2 = 0.f, a3 = 0.f;   // 4-way ILP
        #pragma unroll 8
        for (int r = 0; r < 128; r += 4) {
            a0 = fmaf(g[r + 0], w[(size_t)(r + 0) * HID], a0);
            a1 = fmaf(g[r + 1], w[(size_t)(r + 1) * HID], a1);
            a2 = fmaf(g[r + 2], w[(size_t)(r + 2) * HID], a2);
            a3 = fmaf(g[r + 3], w[(size_t)(r + 3) * HID], a3);
        }
        hpart[((size_t)i * 16 + ky) * HID + k] = (a0 + a1) + (a2 + a3);
    } else if (bid < 608) {
        int tg = (bid - 512) * 256 + tid;            // 0..24575
        if (tg < 8192) {
            // W2 pack for 32x32x16 A-frags: frag F = mt2*16 + ks (mt2 0..7, ks 0..15);
            // lane l elem r: A[m = mt2*32 + (l&31)][k = ks*16 + (l>>5)*8 + r] = W2[k][m]
            int t = tg, F = t >> 6, l = t & 63;
            int mt2 = F >> 4, ks = F & 15;
            int kb = ks * 16 + (l >> 5) * 8;
            int n  = mt2 * 32 + (l & 31);
            _Float16* o = W2G + (size_t)t * 8;
            #pragma unroll
            for (int j = 0; j < 8; j++) o[j] = (_Float16)W2[(size_t)(kb + j) * HID + n];
        } else {
            int t = tg - 8192, F = t >> 6, l = t & 63;
            int k2t = F >> 4, ks = F & 15;
            int kb = ks * 32 + (l >> 4) * 8;
            int n  = k2t * 16 + (l & 15);
            const float* W1c = W1 + (size_t)DD * HID;
            _Float16* o = W1F + (size_t)t * 8;
            #pragma unroll
            for (int j = 0; j < 8; j++) o[j] = (_Float16)W1c[(size_t)(kb + j) * HID + n];
        }
    } else {
        __shared__ _Float16 sT[64][HWP + 4];
        int b = bid - 608;                           // 0..255
        int n = b >> 3, c0 = (b & 7) * 64;
        for (int task = tid; task < 64 * 49; task += 256) {
            int c = task / 49, f = task - c * 49;
            f4 v = *(const f4*)&lf[((size_t)n * CC + c0 + c) * HWP + f * 4];
            h4 o = { (_Float16)v.x, (_Float16)v.y, (_Float16)v.z, (_Float16)v.w };
            *(h4*)&sT[c][f * 4] = o;
        }
        __syncthreads();
        for (int task = tid; task < 8 * HWP; task += 256) {
            int ch = task / HWP, p = task - ch * HWP;
            h8 o;
            #pragma unroll
            for (int cc = 0; cc < 8; cc++) o[cc] = sT[ch * 8 + cc][p];
            *(h8*)&lf16T[((size_t)(n * HWP + p)) * CC + c0 + ch * 8] = o;
        }
    }
}

// ================= hlocF: h_loc = lf16T @ W1[D:], MFMA, ROW-MAJOR [j][k2] output =================
__global__ __launch_bounds__(256, 2) void hlocF_kernel(const _Float16* __restrict__ lf16T,
                                                       const _Float16* __restrict__ W1F,
                                                       const float* __restrict__ hpart,
                                                       const float* __restrict__ b1,
                                                       _Float16* __restrict__ g16,
                                                       _Float16* __restrict__ hL) {
    if (blockIdx.x == 196) {
        int kh = blockIdx.y;
        for (int x = threadIdx.x; x < 16 * HID; x += 256) {
            int i = kh * 16 + (x >> 8), k = x & 255;
            float s = b1[k];
            #pragma unroll
            for (int ky = 0; ky < 16; ky++) s += hpart[((size_t)i * 16 + ky) * HID + k];
            g16[(size_t)i * HID + k] = (_Float16)s;
        }
        return;
    }
    __shared__ _Float16 sLf[32][CC + 16];
    int tid = threadIdx.x;
    int w = tid >> 6, l = tid & 63, quad = l >> 4, ln = l & 15;
    int j0 = blockIdx.x * 32;
    int khalf = blockIdx.y;

    #pragma unroll
    for (int s = 0; s < 8; s++) {
        int y = s * 256 + tid;
        int row = y >> 6, col = (y & 63) * 8;
        h8 v = *(const h8*)&lf16T[(size_t)(j0 + row) * CC + col];
        *(h8*)&sLf[row][col] = v;
    }

    F4H8 Af[32];
    {
        const f4* src = (const f4*)W1F + l;
        #pragma unroll
        for (int mt = 0; mt < 2; mt++)
            #pragma unroll
            for (int ks = 0; ks < 16; ks++)
                Af[mt * 16 + ks].f = src[(size_t)((khalf * 8 + w * 2 + mt) * 16 + ks) * 64];
    }
    __syncthreads();

    f4 acc[4] = {};
    #pragma unroll
    for (int ks = 0; ks < 16; ks++) {
        h8 bF[2];
        #pragma unroll
        for (int nt = 0; nt < 2; nt++)
            bF[nt] = *(const h8*)&sLf[nt * 16 + ln][ks * 32 + quad * 8];
        #pragma unroll
        for (int mt = 0; mt < 2; mt++)
            #pragma unroll
            for (int nt = 0; nt < 2; nt++)
                acc[mt * 2 + nt] = __builtin_amdgcn_mfma_f32_16x16x32_f16(Af[mt * 16 + ks].h, bF[nt], acc[mt * 2 + nt], 0, 0, 0);
    }

    // row-major packed h4 store: h_loc[j][k2], 4 consecutive k2 per reg group
    #pragma unroll
    for (int mt = 0; mt < 2; mt++)
        #pragma unroll
        for (int nt = 0; nt < 2; nt++) {
            int j  = j0 + nt * 16 + ln;
            int k2 = khalf * 128 + w * 32 + mt * 16 + quad * 4;
            h4 o = { (_Float16)acc[mt * 2 + nt][0], (_Float16)acc[mt * 2 + nt][1],
                     (_Float16)acc[mt * 2 + nt][2], (_Float16)acc[mt * 2 + nt][3] };
            *(h4*)&hL[(size_t)j * HID + k2] = o;
        }
}

// ================= score v9: 32x32x16, frag-lane staging (0-conflict), dbuf, 256-reg tier =================
// R9 fixes, both counter-verified defects:
//  (1) 2.4M bank conflicts were the staging ds_writes (bank=(sj&7)*4, 8-way). New writer
//      mapping t -> (frag f=(t>>6)*8+r, lane L=t&63): per wave-instruction f is uniform,
//      addr = base + lane*16B -> contiguous 1KB, 0 conflicts (same pattern as the reads).
//      Cost moved to global side: strided 32B gathers from L2-resident hL (~5us worst).
//  (2) 10.9MB scratch at VGPR=128: allocator picks the tier matching LDS-implied occupancy
//      (34KB -> 4 blk/CU -> 128 regs) and spills. Fix by construction: double-buffer sB
//      (66.6KB LDS) -> 2 blk/CU -> 2 waves/SIMD -> 256-reg budget; Af 128 + acc 32 fits.
//      The dbuf is also productive: stage(i0+1) issues before compute(i0), hiding staging
//      latency under the MFMA pass.
// Grid (16, 98), 256 thr = 4 waves x 64 k2 (2 M-tiles each), 2 MFMAs per B-read.
__global__ __launch_bounds__(256, 2)
void score_kernel(const _Float16* __restrict__ hL,
                  const _Float16* __restrict__ g16,
                  const _Float16* __restrict__ W2G,
                  const float* __restrict__ b2,
                  const float* __restrict__ W3,
                  const float* __restrict__ b3,
                  float* __restrict__ scores) {
    __shared__ _Float16 sB[2][64 * HID];  // 2 x 32 KB, frag-ordered h1 tiles
    __shared__ float sRed[4][68];         // [wave][j-local]
    int tid = threadIdx.x, w = tid >> 6, l = tid & 63;
    int hi = l >> 5, ln32 = l & 31;
    int i0 = blockIdx.x * 2, jt = blockIdx.y;   // jt 0..97
    int j0 = jt * 64;

    // A-frags: wave w owns k2-slice [w*64, w*64+64) = M-tiles 2w, 2w+1 (32 frags, 128 VGPR)
    F4H8 Af[2][16];
    {
        const f4* src = (const f4*)W2G + l;
        #pragma unroll
        for (int a = 0; a < 2; a++)
            #pragma unroll
            for (int ks = 0; ks < 16; ks++)
                Af[a][ks].f = src[(size_t)((w * 2 + a) * 16 + ks) * 64];
    }
    float bias3 = b3[0];
    h8 z = {};
    int fb = (tid >> 6) * 8;              // frag base for this thread's wave

    // STAGE(buf, i): frag-lane order. f = fb + r, L = l. Source cell:
    //   j = (f>>4)*32 + (L&31), o = (f&15)*2 + (L>>5)  (o = k-octet index)
    #define STAGE(BUF, I)                                                              \
    {                                                                                  \
        const _Float16* gB = g16 + (size_t)(I) * HID;                                  \
        _Pragma("unroll")                                                              \
        for (int r = 0; r < 8; r++) {                                                  \
            int f = fb + r;                                                            \
            int j = ((f >> 4) << 5) + (l & 31);                                        \
            int o = ((f & 15) << 1) + hi;                                              \
            h8 hv = *(const h8*)&hL[(size_t)(j0 + j) * HID + o * 8];                   \
            h8 gq = *(const h8*)&gB[o * 8];                                            \
            *(h8*)&sB[BUF][f * 512 + l * 8] = __builtin_elementwise_max(hv + gq, z);   \
        }                                                                              \
    }

    STAGE(0, i0);
    __syncthreads();
    STAGE(1, i0 + 1);                     // overlaps with ii=0 compute below

    #pragma unroll 1
    for (int ii = 0; ii < 2; ii++) {
        #pragma unroll 1
        for (int ntg = 0; ntg < 2; ntg++) {
            f16v acc[2] = {};
            #pragma unroll
            for (int ks = 0; ks < 16; ks++) {
                h8 bz = *(const h8*)&sB[ii][(ntg * 16 + ks) * 512 + l * 8];
                acc[0] = __builtin_amdgcn_mfma_f32_32x32x16_f16(Af[0][ks].h, bz, acc[0], 0, 0, 0);
                acc[1] = __builtin_amdgcn_mfma_f32_32x32x16_f16(Af[1][ks].h, bz, acc[1], 0, 0, 0);
            }
            // epilogue: C[m][n]: n=l&31 (j), m=(r&3)+8*(r>>2)+4*hi; s_j += relu(acc+b2)*W3
            float s = 0.f;
            #pragma unroll
            for (int a = 0; a < 2; a++) {
                int kb = w * 64 + a * 32 + 4 * hi;
                #pragma unroll
                for (int q = 0; q < 4; q++) {
                    f4 b2v = *(const f4*)&b2[kb + q * 8];
                    f4 w3v = *(const f4*)&W3[kb + q * 8];
                    s += fmaxf(acc[a][q * 4 + 0] + b2v.x, 0.f) * w3v.x
                       + fmaxf(acc[a][q * 4 + 1] + b2v.y, 0.f) * w3v.y
                       + fmaxf(acc[a][q * 4 + 2] + b2v.z, 0.f) * w3v.z
                       + fmaxf(acc[a][q * 4 + 3] + b2v.w, 0.f) * w3v.w;
                }
            }
            s += __shfl_xor(s, 32, 64);
            if (hi == 0) sRed[w][ntg * 32 + ln32] = s;
        }
        __syncthreads();                  // sRed ready; (ii=0) also orders STAGE(1) completion
        if (tid < 64) {
            scores[(size_t)(i0 + ii) * NHW + j0 + tid] =
                sRed[0][tid] + sRed[1][tid] + sRed[2][tid] + sRed[3][tid] + bias3;
        }
        if (ii == 0) __syncthreads();     // protect sRed before ii=1 epilogue rewrites it
    }
    #undef STAGE
}

// ================= reduce: single-pass online masked log-mean-exp =================
__global__ __launch_bounds__(1024) void reduce_kernel(const float* __restrict__ scores,
                                                      float* __restrict__ out) {
    int i = blockIdx.x, tid = threadIdx.x;
    const float* row = scores + (size_t)i * NHW;
    const f4* row4 = (const f4*)row;                 // 1568 f4
    __shared__ float sM[16], sT[16], sO[16], sval[1];
    int q0 = i * 49, q1 = q0 + 49;
    float m = -1e30f, t = 0.f, o = 0.f;
    for (int q = tid; q < 1568; q += 1024) {
        f4 v = row4[q];
        float vm = fmaxf(fmaxf(v.x, v.y), fmaxf(v.z, v.w));
        float nm = fmaxf(m, vm);
        float sc = expf(m - nm);
        float e = expf(v.x - nm) + expf(v.y - nm) + expf(v.z - nm) + expf(v.w - nm);
        t = t * sc + e;
        o *= sc;
        if (q >= q0 && q < q1) o += e;
        m = nm;
    }
    #pragma unroll
    for (int off = 32; off > 0; off >>= 1) {
        float m2 = __shfl_xor(m, off, 64);
        float t2 = __shfl_xor(t, off, 64);
        float o2 = __shfl_xor(o, off, 64);
        float nm = fmaxf(m, m2);
        float sa = expf(m - nm), sb = expf(m2 - nm);
        t = t * sa + t2 * sb;
        o = o * sa + o2 * sb;
        m = nm;
    }
    if ((tid & 63) == 0) { sM[tid >> 6] = m; sT[tid >> 6] = t; sO[tid >> 6] = o; }
    __syncthreads();
    if (tid == 0) {
        float M = sM[0], T = sT[0], O = sO[0];
        for (int c = 1; c < 16; c++) {
            float nm = fmaxf(M, sM[c]);
            float sa = expf(M - nm), sb = expf(sM[c] - nm);
            T = T * sa + sT[c] * sb;
            O = O * sa + sO[c] * sb;
            M = nm;
        }
        float neg_mean = (T - O) / (float)(NHW - HWP) + 1e-10f;
        sval[0] = M + logf(neg_mean);
    }
    __syncthreads();
    float sub = sval[0];
    if (tid < HWP) out[(size_t)i * HWP + tid] = row[i * HWP + tid] - sub;
}

extern "C" void kernel_launch(void* const* d_in, const int* in_sizes, int n_in,
                              void* d_out, int out_size, void* d_ws, size_t ws_size,
                              hipStream_t stream) {
    const float* lf = (const float*)d_in[0];
    const float* gf = (const float*)d_in[1];
    const float* W1 = (const float*)d_in[2];
    const float* b1 = (const float*)d_in[3];
    const float* W2 = (const float*)d_in[4];
    const float* b2 = (const float*)d_in[5];
    const float* W3 = (const float*)d_in[6];
    const float* b3 = (const float*)d_in[7];
    float* out = (float*)d_out;

    char* ws = (char*)d_ws;
    _Float16* hL     = (_Float16*)ws;                      // 3,211,264 B  (row-major h_loc)
    _Float16* g16    = (_Float16*)(ws + 3211264);          // 16 KB
    _Float16* W2G    = (_Float16*)(ws + 3227648);          // 128 KB (32x32 frag pack)
    _Float16* W1F    = (_Float16*)(ws + 3358720);          // 256 KB
    _Float16* lf16T  = (_Float16*)(ws + 3620864);          // 6,422,528 B
    float*    scores = (float*)   (ws + 10043392);         // 802,816 B
    float*    hpart  = (float*)   (ws + 10846208);         // 524,288 B

    hipLaunchKernelGGL(prep_kernel, dim3(864), dim3(256), 0, stream,
                       lf, gf, W1, W2, hpart, W2G, W1F, lf16T);
    hipLaunchKernelGGL(hlocF_kernel, dim3(197, 2), dim3(256), 0, stream,
                       lf16T, W1F, hpart, b1, g16, hL);
    hipLaunchKernelGGL(score_kernel, dim3(16, 98), dim3(256), 0, stream,
                       hL, g16, W2G, b2, W3, b3, scores);
    hipLaunchKernelGGL(reduce_kernel, dim3(NB), dim3(1024), 0, stream, scores, out);
}